// Round 19
// baseline (214.990 us; speedup 1.0000x reference)
//
#include <hip/hip_runtime.h>
#include <hip/hip_bf16.h>

typedef short bf16x8 __attribute__((ext_vector_type(8)));
typedef float f32x4 __attribute__((ext_vector_type(4)));
typedef float f32x16 __attribute__((ext_vector_type(16)));
typedef unsigned int u32x4 __attribute__((ext_vector_type(4)));
typedef unsigned short u16;
typedef unsigned short u16x4 __attribute__((ext_vector_type(4)));
typedef unsigned short u16x8 __attribute__((ext_vector_type(8)));

constexpr int D_IN = 2048, D_OUT = 2048, NH = 16, HD = 128, LAT = 256;
constexpr int Bb = 2, Ss = 2048, Mtot = Bb * Ss;  // 4096

constexpr float QSCALE = 0.08838834764831845f * 1.4426950408889634f;
constexpr float NEG_BIG = -3.0e38f;

__device__ __forceinline__ u16 f2bf(float f) {
  unsigned u = __float_as_uint(f);
  unsigned r = ((u >> 16) & 1u) + 0x7fffu;  // RNE
  return (u16)((u + r) >> 16);
}

__device__ __forceinline__ float bf2f(u16 v) {
  return __uint_as_float((unsigned)v << 16);
}

__device__ __forceinline__ float fexp2(float x) {
#if __has_builtin(__builtin_amdgcn_exp2f)
  return __builtin_amdgcn_exp2f(x);
#else
  return exp2f(x);
#endif
}

__device__ __forceinline__ unsigned cvtpk(float lo, float hi) {
  unsigned r;
  asm("v_cvt_pk_bf16_f32 %0, %1, %2" : "=v"(r) : "v"(lo), "v"(hi));
  return r;
}

__device__ __forceinline__ void swap32(unsigned& a, unsigned& b) {
  asm volatile("v_permlane32_swap_b32 %0, %1" : "+v"(a), "+v"(b));
}

__device__ __forceinline__ void gload_lds16(const u16* g, u16* l) {
  __builtin_amdgcn_global_load_lds((const __attribute__((address_space(1))) void*)g,
                                   (__attribute__((address_space(3))) void*)l, 16, 0, 0);
}

// ---------- merged convert: x f32->bf16 (blocks 0..8191) + 4 weight
// transposes [K][N] f32 -> [N][K] bf16 (blocks 8192..17919), one dispatch ----
__global__ void k_cvt_all(const float* __restrict__ x, u16* __restrict__ xb,
                          const float* __restrict__ w0, u16* __restrict__ o0,
                          const float* __restrict__ w1, u16* __restrict__ o1,
                          const float* __restrict__ w2, u16* __restrict__ o2,
                          const float* __restrict__ w3, u16* __restrict__ o3) {
  int id = blockIdx.x;
  const int tx = threadIdx.x, ty = threadIdx.y;
  if (id < 8192) {  // flat convert: 1024 elems per block
    const int i = id * 1024 + (ty * 32 + tx) * 4;
    float4 v = *reinterpret_cast<const float4*>(x + i);
    ushort4 o;
    o.x = f2bf(v.x); o.y = f2bf(v.y); o.z = f2bf(v.z); o.w = f2bf(v.w);
    *reinterpret_cast<ushort4*>(xb + i) = o;
    return;
  }
  id -= 8192;
  __shared__ float t[32][33];
  const float* in;
  u16* out;
  int K, N, bx, by;
  if (id < 4096)      { in = w0; out = o0; K = 2048; N = 2048; bx = (id & 63) * 32; by = (id >> 6) * 32; }
  else if (id < 4608) { id -= 4096; in = w1; out = o1; K = 2048; N = 256;  bx = (id & 7) * 32;  by = (id >> 3) * 32; }
  else if (id < 5632) { id -= 4608; in = w2; out = o2; K = 256;  N = 4096; bx = (id & 127) * 32; by = (id >> 7) * 32; }
  else                { id -= 5632; in = w3; out = o3; K = 2048; N = 2048; bx = (id & 63) * 32; by = (id >> 6) * 32; }
#pragma unroll
  for (int j = 0; j < 32; j += 8)
    t[ty + j][tx] = in[(size_t)(by + ty + j) * N + bx + tx];
  __syncthreads();
#pragma unroll
  for (int j = 0; j < 32; j += 8)
    out[(size_t)(bx + ty + j) * K + by + tx] = f2bf(t[tx][ty + j]);
}

// ---------- GEMM: C[M,N] = A[M,K](bf16 rm) x Bt[N,K](bf16 rm)^T ----------
// 128x128 tile, BK=64, 4 waves, 2 barriers per 64-K; both-sides XOR swizzle.
// OUT_MODE 0: bf16; 1: f32 + bias; 3: split (c<2048 -> Cp*scale, else Cp2).
template <int OUT_MODE>
__global__ __launch_bounds__(256) void k_gemm(const u16* __restrict__ A,
                                              const u16* __restrict__ Bt,
                                              void* __restrict__ Cp,
                                              void* __restrict__ Cp2,
                                              const float* __restrict__ bias,
                                              float scale, int M, int N, int K) {
  constexpr int BK = 64;
  __shared__ __align__(16) u16 As[128 * BK];  // 16 KB
  __shared__ __align__(16) u16 Bs[128 * BK];  // 16 KB
  const int nwg = gridDim.x;
  int bid = blockIdx.x;
  bid = (bid & 7) * (nwg >> 3) + (bid >> 3);  // bijective XCD swizzle (nwg%8==0)
  const int nbx = N >> 7;
  const int bx = bid % nbx, by = bid / nbx;
  const int row0 = by << 7, col0 = bx << 7;
  const int tid = threadIdx.x;
  const int wave = tid >> 6, lane = tid & 63;
  const int wr = (wave >> 1) * 64, wc = (wave & 1) * 64;
  const int lr = lane & 15, lg = lane >> 4;

  f32x4 acc[4][4];
#pragma unroll
  for (int m = 0; m < 4; ++m)
#pragma unroll
    for (int n = 0; n < 4; ++n) acc[m][n] = (f32x4)0.0f;

  const int srow = wave * 32 + (lane >> 3);
  const int scol = ((lane & 7) ^ (lane >> 3)) * 8;
  const u16* gA = A + (size_t)(row0 + srow) * K + scol;
  const u16* gB = Bt + (size_t)(col0 + srow) * K + scol;
  const size_t rstep = (size_t)8 * K;
  u16* lA = &As[(wave * 32) * BK];
  u16* lB = &Bs[(wave * 32) * BK];

  const int rsw = (lr & 7) * 8;  // read-side swizzle

  for (int k0 = 0; k0 < K; k0 += BK) {
#pragma unroll
    for (int c = 0; c < 4; ++c) {
      gload_lds16(gA + c * rstep + k0, lA + c * 8 * BK);
      gload_lds16(gB + c * rstep + k0, lB + c * 8 * BK);
    }
    __syncthreads();
#pragma unroll
    for (int sub = 0; sub < 2; ++sub) {
      const int co = (sub * 32 + lg * 8) ^ rsw;
      bf16x8 af[4], bfr[4];
#pragma unroll
      for (int m = 0; m < 4; ++m)
        af[m] = *reinterpret_cast<const bf16x8*>(&As[(wr + m * 16 + lr) * BK + co]);
#pragma unroll
      for (int n = 0; n < 4; ++n)
        bfr[n] = *reinterpret_cast<const bf16x8*>(&Bs[(wc + n * 16 + lr) * BK + co]);
#pragma unroll
      for (int m = 0; m < 4; ++m)
#pragma unroll
        for (int n = 0; n < 4; ++n)
          acc[m][n] = __builtin_amdgcn_mfma_f32_16x16x32_bf16(af[m], bfr[n], acc[m][n], 0, 0, 0);
    }
    __syncthreads();
  }

#pragma unroll
  for (int m = 0; m < 4; ++m) {
    const int r = row0 + wr + m * 16 + lg * 4;
#pragma unroll
    for (int n = 0; n < 4; ++n) {
      const int c = col0 + wc + n * 16 + lr;
#pragma unroll
      for (int i = 0; i < 4; ++i) {
        float v = acc[m][n][i];
        if (OUT_MODE == 0)
          ((u16*)Cp)[(size_t)(r + i) * N + c] = f2bf(v);
        else if (OUT_MODE == 1)
          ((float*)Cp)[(size_t)(r + i) * N + c] = v + bias[c];
        else {  // 3: q | latent split
          if (c < 2048)
            ((u16*)Cp)[(size_t)(r + i) * 2048 + c] = f2bf(v * scale);
          else
            ((u16*)Cp2)[(size_t)(r + i) * 256 + (c - 2048)] = f2bf(v);
        }
      }
    }
  }
}

// ---------- causal flash attention: 8-wave blocks, 256 q-rows, KVBLK=128 ----------
// 16 equal jobs per bh (8x5-tile + 8x4-tile, <=2 chained segments), 512 blocks
// = exactly 2/CU; 5-tile jobs are blocks 0..255, 4-tile 256..511 -> paired 5+4
// per CU = uniform 9 tile-slots with inter-block stall overlap.
// Strip part slots per bh: s1:0(2) s2:2(2) s3:4(2) s4:6(3) s5:9(3) s6:12(3)
// s7:15(4) -> 19 slots. s0 runs whole. Fixed-max softmax.
__device__ __constant__ const signed char S_qb[32] = {
  7,0, 7,0, 7,0, 7,6, 6,0, 6,0, 5,0, 5,0,     // jobs 0..7 (5 tiles)
  5,4, 4,0, 4,0, 3,0, 3,0, 2,0, 2,1, 1,0};    // jobs 8..15 (4 tiles)
__device__ __constant__ const signed char S_k0[32] = {
  0,0, 5,0, 10,0, 15,0, 4,0, 9,0, 0,0, 5,0,
  10,0, 2,0, 6,0, 0,0, 4,0, 0,0, 4,0, 2,0};
__device__ __constant__ const signed char S_k1[32] = {
  5,0, 10,0, 15,0, 16,4, 9,0, 14,0, 5,0, 10,0,
  12,2, 6,0, 10,0, 4,0, 8,0, 4,0, 6,2, 4,2};
__device__ __constant__ const signed char S_sl[32] = {
  15,0, 16,0, 17,0, 18,12, 13,0, 14,0, 9,0, 10,0,
  11,6, 7,0, 8,0, 4,0, 5,0, 2,0, 3,0, 1,-1};

__global__ __launch_bounds__(512) void k_attn(const u16* __restrict__ Q,
                                              const u16* __restrict__ KV,
                                              u16* __restrict__ O,
                                              u16* __restrict__ o_part,
                                              float* __restrict__ lbuf) {
  __shared__ __align__(16) u16 Ks[128 * 128];
  __shared__ __align__(16) u16 Vt[128 * 128];
  const int job = blockIdx.x >> 5, bh = blockIdx.x & 31;
  const int b = bh >> 4, h = bh & 15;
  const u16* Qb = Q + (size_t)b * Ss * D_OUT + h * HD;
  const u16* Kb = KV + (size_t)b * Ss * (2 * D_OUT) + h * HD;
  const u16* Vb = Kb + D_OUT;
  u16* Ob = O + (size_t)b * Ss * D_OUT + h * HD;

  const int tid = threadIdx.x, wave = tid >> 6, lane = tid & 63;
  const int lo = lane & 31, hi = lane >> 5;

  const int sr = tid >> 2, sc = tid & 3;
  const int vk = (tid & 31) * 4, vd = (tid >> 5) * 8;
  const size_t kvstep = (size_t)128 * 2 * D_OUT;
  const int ksw = (sr & 7) ^ (((sr >> 3) & 3) << 1);
  const int krd = ((lo & 7) * 8) ^ (((lo >> 3) & 3) << 4);

  for (int seg = 0; seg < 2; ++seg) {
    const int kt1 = S_k1[job * 2 + seg];
    if (kt1 == 0) break;  // no second segment
    const int qb = S_qb[job * 2 + seg];
    const int kt0 = S_k0[job * 2 + seg];
    const int sl = S_sl[job * 2 + seg];  // -1 whole, else part slot
    const int q0w = qb * 256 + wave * 32;

    // Q fragments for this segment
    bf16x8 qf[8];
    {
      const u16* qsrc = Qb + (size_t)(q0w + lo) * D_OUT + hi * 8;
#pragma unroll
      for (int ds = 0; ds < 8; ++ds)
        qf[ds] = *reinterpret_cast<const bf16x8*>(qsrc + ds * 16);
    }

    f32x16 ctx[4];
#pragma unroll
    for (int dt = 0; dt < 4; ++dt) ctx[dt] = (f32x16)0.0f;
    float lrow = 0.0f;

    const u16* kg = Kb + (size_t)kt0 * kvstep + (size_t)sr * (2 * D_OUT) + sc * 8;
    const u16* vg = Vb + (size_t)kt0 * kvstep + (size_t)vk * (2 * D_OUT) + vd;

    int4 kreg[4];
    u16x8 vreg[4];
#pragma unroll
    for (int c = 0; c < 4; ++c) {
      kreg[c] = *reinterpret_cast<const int4*>(kg + c * 32);
      vreg[c] = *reinterpret_cast<const u16x8*>(vg + (size_t)c * (2 * D_OUT));
    }

    for (int kt = kt0; kt < kt1; ++kt) {
#pragma unroll
      for (int c = 0; c < 4; ++c)
        *reinterpret_cast<int4*>(&Ks[sr * 128 + (((sc + 4 * c) ^ ksw) * 8)]) = kreg[c];
#pragma unroll
      for (int jj = 0; jj < 8; ++jj) {
        const int vcol = (vk ^ (jj * 8)) ^ ((((vd + jj) >> 3) & 3) << 4);
        u16x4 pk = {vreg[0][jj], vreg[1][jj], vreg[2][jj], vreg[3][jj]};
        *reinterpret_cast<u16x4*>(&Vt[(vd + jj) * 128 + vcol]) = pk;
      }
      if (kt + 1 < kt1) {
        const u16* kn = kg + (size_t)(kt + 1 - kt0) * kvstep;
        const u16* vn = vg + (size_t)(kt + 1 - kt0) * kvstep;
#pragma unroll
        for (int c = 0; c < 4; ++c) {
          kreg[c] = *reinterpret_cast<const int4*>(kn + c * 32);
          vreg[c] = *reinterpret_cast<const u16x8*>(vn + (size_t)c * (2 * D_OUT));
        }
      }
      __syncthreads();

#pragma unroll
      for (int sub = 0; sub < 2; ++sub) {
        const int kbs = kt * 128 + sub * 64;
        if (kbs <= q0w + 31) {
          f32x16 s0 = (f32x16)0.0f, s1 = (f32x16)0.0f;
          __builtin_amdgcn_s_setprio(1);
#pragma unroll
          for (int ds = 0; ds < 8; ++ds) {
            const int off = (16 * ds + 8 * hi) ^ krd;
            bf16x8 a0 = *reinterpret_cast<const bf16x8*>(&Ks[(sub * 64 + lo) * 128 + off]);
            bf16x8 a1 = *reinterpret_cast<const bf16x8*>(&Ks[(sub * 64 + 32 + lo) * 128 + off]);
            s0 = __builtin_amdgcn_mfma_f32_32x32x16_bf16(a0, qf[ds], s0, 0, 0, 0);
            s1 = __builtin_amdgcn_mfma_f32_32x32x16_bf16(a1, qf[ds], s1, 0, 0, 0);
          }
          __builtin_amdgcn_s_setprio(0);

          if (kbs + 63 > q0w) {
            const int qg = q0w + lo;
#pragma unroll
            for (int r = 0; r < 16; ++r) {
              const int koff = kbs + (r & 3) + 8 * (r >> 2) + 4 * hi;
              if (koff > qg) s0[r] = NEG_BIG;
              if (koff + 32 > qg) s1[r] = NEG_BIG;
            }
          }

#pragma unroll
          for (int r = 0; r < 16; ++r) s0[r] = fexp2(s0[r]);
#pragma unroll
          for (int r = 0; r < 16; ++r) s1[r] = fexp2(s1[r]);

          bf16x8 pa[4];
#pragma unroll
          for (int g = 0; g < 2; ++g) {
            const f32x16& sg = g ? s1 : s0;
#pragma unroll
            for (int half = 0; half < 2; ++half) {
              const int rb = half * 8;
              unsigned w0 = cvtpk(sg[rb + 0], sg[rb + 1]);
              unsigned w2 = cvtpk(sg[rb + 4], sg[rb + 5]);
              unsigned w1 = cvtpk(sg[rb + 2], sg[rb + 3]);
              unsigned w3 = cvtpk(sg[rb + 6], sg[rb + 7]);
              swap32(w0, w2);
              swap32(w1, w3);
              u32x4 fr = {w0, w1, w2, w3};
              pa[2 * g + half] = __builtin_bit_cast(bf16x8, fr);
            }
          }

          __builtin_amdgcn_s_setprio(1);
#pragma unroll
          for (int dt = 0; dt < 4; ++dt) {
            const int vrow = 32 * dt + lo;
#pragma unroll
            for (int ks = 0; ks < 4; ++ks) {
              const int off = sub * 64 + ((16 * ks + 8 * hi) ^ krd);
              bf16x8 bv = *reinterpret_cast<const bf16x8*>(&Vt[vrow * 128 + off]);
              ctx[dt] = __builtin_amdgcn_mfma_f32_32x32x16_bf16(pa[ks], bv, ctx[dt], 0, 0, 0);
            }
          }
          __builtin_amdgcn_s_setprio(0);

          float sm[16];
#pragma unroll
          for (int r = 0; r < 16; ++r) sm[r] = s0[r] + s1[r];
#pragma unroll
          for (int w = 8; w >= 1; w >>= 1)
#pragma unroll
            for (int r = 0; r < w; ++r) sm[r] += sm[r + w];
          lrow += sm[0] + __shfl_xor(sm[0], 32);
        }
      }
      __syncthreads();
    }

    if (sl < 0) {
      // whole strip: normalize + store bf16 ctx
      float linv = 1.0f / lrow;
#pragma unroll
      for (int r = 0; r < 16; ++r) {
        float lb = __shfl(linv, ((r & 3) + 8 * (r >> 2)) + 4 * hi);
        const int qr = q0w + (r & 3) + 8 * (r >> 2) + 4 * hi;
#pragma unroll
        for (int dt = 0; dt < 4; ++dt)
          Ob[(size_t)qr * D_OUT + dt * 32 + lo] = f2bf(ctx[dt][r] * lb);
      }
    } else {
      // split strip part: store unnormalized partial + per-row l
      const int pi = bh * 19 + sl;
      u16* po = o_part + (size_t)pi * (256 * 128);
      float* pl = lbuf + (size_t)pi * 256;
#pragma unroll
      for (int r = 0; r < 16; ++r) {
        const int rl = wave * 32 + (r & 3) + 8 * (r >> 2) + 4 * hi;
#pragma unroll
        for (int dt = 0; dt < 4; ++dt)
          po[rl * 128 + dt * 32 + lo] = f2bf(ctx[dt][r]);
      }
      if (hi == 0) pl[wave * 32 + lo] = lrow;
    }
    __syncthreads();  // LDS safe before next segment's staging
  }
}

// ---------- combine split-strip partials (strips 1..7, 2-4 parts) ----------
__device__ __constant__ const signed char C_np[7]   = {2, 2, 2, 3, 3, 3, 4};
__device__ __constant__ const signed char C_base[7] = {0, 2, 4, 6, 9, 12, 15};

__global__ __launch_bounds__(256) void k_comb(const u16* __restrict__ o_part,
                                              const float* __restrict__ lbuf,
                                              u16* __restrict__ O) {
  const int sb = blockIdx.x >> 2;   // strip idx 0..223
  const int rg = blockIdx.x & 3;    // row group (64 rows)
  const int bh = sb / 7, js = sb % 7, qb = js + 1;
  const int np = C_np[js];
  const int b = bh >> 4, h = bh & 15;
  u16* Ob = O + (size_t)b * Ss * D_OUT + h * HD;
  const int base = bh * 19 + C_base[js];
  const u16* po = o_part + (size_t)base * (256 * 128);
  const float* pl = lbuf + (size_t)base * 256;
  const int tid = threadIdx.x;
  const int r0 = tid >> 4, dg = (tid & 15) * 8;
#pragma unroll
  for (int rp = 0; rp < 4; ++rp) {
    const int row = rg * 64 + rp * 16 + r0;
    float lsum = 0.0f;
    for (int pp = 0; pp < np; ++pp) lsum += pl[pp * 256 + row];
    const float inv = 1.0f / lsum;
    float acc[8];
#pragma unroll
    for (int j = 0; j < 8; ++j) acc[j] = 0.0f;
    for (int pp = 0; pp < np; ++pp) {
      u16x8 ov = *reinterpret_cast<const u16x8*>(po + (size_t)pp * 32768 + row * 128 + dg);
#pragma unroll
      for (int j = 0; j < 8; ++j) acc[j] += bf2f(ov[j]);
    }
    u16x8 o;
#pragma unroll
    for (int j = 0; j < 8; ++j) o[j] = f2bf(acc[j] * inv);
    *reinterpret_cast<u16x8*>(&Ob[(size_t)(qb * 256 + row) * D_OUT + dg]) = o;
  }
}

extern "C" void kernel_launch(void* const* d_in, const int* in_sizes, int n_in,
                              void* d_out, int out_size, void* d_ws, size_t ws_size,
                              hipStream_t stream) {
  const float* x    = (const float*)d_in[0];
  const float* Wq   = (const float*)d_in[1];
  const float* Wdkv = (const float*)d_in[2];
  const float* Wukv = (const float*)d_in[3];
  const float* Wout = (const float*)d_in[4];
  const float* bout = (const float*)d_in[5];
  float* out = (float*)d_out;

  char* ws = (char*)d_ws;
  size_t off = 0;
  auto alloc = [&](size_t bytes) -> void* {
    void* p = ws + off;
    off += (bytes + 255) & ~(size_t)255;
    return p;
  };
  u16* xb    = (u16*)alloc((size_t)Mtot * D_IN * 2);
  u16* wcat  = (u16*)alloc((size_t)(D_OUT + LAT) * D_IN * 2);  // [Wq^T ; Wdkv^T]
  u16* wukvT = (u16*)alloc((size_t)2 * D_OUT * LAT * 2);
  u16* woutT = (u16*)alloc((size_t)D_IN * D_OUT * 2);
  u16* q     = (u16*)alloc((size_t)Mtot * D_OUT * 2);
  u16* lat   = (u16*)alloc((size_t)Mtot * LAT * 2);
  u16* kv    = (u16*)alloc((size_t)Mtot * 2 * D_OUT * 2);
  u16* ctx   = (u16*)alloc((size_t)Mtot * D_OUT * 2);
  u16* opart = (u16*)alloc((size_t)32 * 19 * 256 * 128 * 2);  // 39.8 MB
  float* lbp = (float*)alloc((size_t)32 * 19 * 256 * 4);      // 0.62 MB

  // x convert + all weight transposes in ONE dispatch
  k_cvt_all<<<dim3(8192 + 9728), dim3(32, 8), 0, stream>>>(
      x, xb, Wq, wcat, Wdkv, wcat + (size_t)D_OUT * D_IN, Wukv, wukvT, Wout, woutT);

  // [q | latent] = x @ [Wq | Wdkv]; q scaled by QSCALE in epilogue
  k_gemm<3><<<(Mtot / 128) * ((D_OUT + LAT) / 128), 256, 0, stream>>>(
      xb, wcat, q, lat, nullptr, QSCALE, Mtot, D_OUT + LAT, D_IN);
  // kv = latent @ Wukv
  k_gemm<0><<<(Mtot / 128) * (2 * D_OUT / 128), 256, 0, stream>>>(
      lat, wukvT, kv, nullptr, nullptr, 1.0f, Mtot, 2 * D_OUT, LAT);
  // attention (16 equal jobs x 32 bh = 512 blocks, 2/CU paired 5+4) + combine
  k_attn<<<dim3(16 * 32), 512, 0, stream>>>(q, kv, ctx, opart, lbp);
  k_comb<<<dim3(896), 256, 0, stream>>>(opart, lbp, ctx);
  // out = ctx @ Wout + b_out
  k_gemm<1><<<(Mtot / 128) * (D_IN / 128), 256, 0, stream>>>(
      ctx, woutT, out, nullptr, bout, 1.0f, Mtot, D_IN, D_OUT);
}

// Round 20
// 197.514 us; speedup vs baseline: 1.0885x; 1.0885x over previous
//
#include <hip/hip_runtime.h>
#include <hip/hip_bf16.h>

typedef short bf16x8 __attribute__((ext_vector_type(8)));
typedef float f32x4 __attribute__((ext_vector_type(4)));
typedef float f32x16 __attribute__((ext_vector_type(16)));
typedef unsigned int u32x4 __attribute__((ext_vector_type(4)));
typedef unsigned short u16;
typedef unsigned short u16x4 __attribute__((ext_vector_type(4)));
typedef unsigned short u16x8 __attribute__((ext_vector_type(8)));

constexpr int D_IN = 2048, D_OUT = 2048, NH = 16, HD = 128, LAT = 256;
constexpr int Bb = 2, Ss = 2048, Mtot = Bb * Ss;  // 4096

constexpr float QSCALE = 0.08838834764831845f * 1.4426950408889634f;
constexpr float NEG_BIG = -3.0e38f;

__device__ __forceinline__ u16 f2bf(float f) {
  unsigned u = __float_as_uint(f);
  unsigned r = ((u >> 16) & 1u) + 0x7fffu;  // RNE
  return (u16)((u + r) >> 16);
}

__device__ __forceinline__ float bf2f(u16 v) {
  return __uint_as_float((unsigned)v << 16);
}

__device__ __forceinline__ float fexp2(float x) {
#if __has_builtin(__builtin_amdgcn_exp2f)
  return __builtin_amdgcn_exp2f(x);
#else
  return exp2f(x);
#endif
}

__device__ __forceinline__ unsigned cvtpk(float lo, float hi) {
  unsigned r;
  asm("v_cvt_pk_bf16_f32 %0, %1, %2" : "=v"(r) : "v"(lo), "v"(hi));
  return r;
}

__device__ __forceinline__ void swap32(unsigned& a, unsigned& b) {
  asm volatile("v_permlane32_swap_b32 %0, %1" : "+v"(a), "+v"(b));
}

__device__ __forceinline__ void gload_lds16(const u16* g, u16* l) {
  __builtin_amdgcn_global_load_lds((const __attribute__((address_space(1))) void*)g,
                                   (__attribute__((address_space(3))) void*)l, 16, 0, 0);
}

// ---------- merged convert: x f32->bf16 (blocks 0..8191) + 4 weight
// transposes [K][N] f32 -> [N][K] bf16 (blocks 8192..17919), one dispatch ----
__global__ void k_cvt_all(const float* __restrict__ x, u16* __restrict__ xb,
                          const float* __restrict__ w0, u16* __restrict__ o0,
                          const float* __restrict__ w1, u16* __restrict__ o1,
                          const float* __restrict__ w2, u16* __restrict__ o2,
                          const float* __restrict__ w3, u16* __restrict__ o3) {
  int id = blockIdx.x;
  const int tx = threadIdx.x, ty = threadIdx.y;
  if (id < 8192) {  // flat convert: 1024 elems per block
    const int i = id * 1024 + (ty * 32 + tx) * 4;
    float4 v = *reinterpret_cast<const float4*>(x + i);
    ushort4 o;
    o.x = f2bf(v.x); o.y = f2bf(v.y); o.z = f2bf(v.z); o.w = f2bf(v.w);
    *reinterpret_cast<ushort4*>(xb + i) = o;
    return;
  }
  id -= 8192;
  __shared__ float t[32][33];
  const float* in;
  u16* out;
  int K, N, bx, by;
  if (id < 4096)      { in = w0; out = o0; K = 2048; N = 2048; bx = (id & 63) * 32; by = (id >> 6) * 32; }
  else if (id < 4608) { id -= 4096; in = w1; out = o1; K = 2048; N = 256;  bx = (id & 7) * 32;  by = (id >> 3) * 32; }
  else if (id < 5632) { id -= 4608; in = w2; out = o2; K = 256;  N = 4096; bx = (id & 127) * 32; by = (id >> 7) * 32; }
  else                { id -= 5632; in = w3; out = o3; K = 2048; N = 2048; bx = (id & 63) * 32; by = (id >> 6) * 32; }
#pragma unroll
  for (int j = 0; j < 32; j += 8)
    t[ty + j][tx] = in[(size_t)(by + ty + j) * N + bx + tx];
  __syncthreads();
#pragma unroll
  for (int j = 0; j < 32; j += 8)
    out[(size_t)(bx + ty + j) * K + by + tx] = f2bf(t[tx][ty + j]);
}

// ---------- GEMM: C[M,N] = A[M,K](bf16 rm) x Bt[N,K](bf16 rm)^T ----------
// 128x128 tile, BK=64, 4 waves, 2 barriers per 64-K; both-sides XOR swizzle.
// OUT_MODE 0: bf16; 1: f32 + bias; 3: split (c<2048 -> Cp*scale, else Cp2).
template <int OUT_MODE>
__global__ __launch_bounds__(256) void k_gemm(const u16* __restrict__ A,
                                              const u16* __restrict__ Bt,
                                              void* __restrict__ Cp,
                                              void* __restrict__ Cp2,
                                              const float* __restrict__ bias,
                                              float scale, int M, int N, int K) {
  constexpr int BK = 64;
  __shared__ __align__(16) u16 As[128 * BK];  // 16 KB
  __shared__ __align__(16) u16 Bs[128 * BK];  // 16 KB
  const int nwg = gridDim.x;
  int bid = blockIdx.x;
  bid = (bid & 7) * (nwg >> 3) + (bid >> 3);  // bijective XCD swizzle (nwg%8==0)
  const int nbx = N >> 7;
  const int bx = bid % nbx, by = bid / nbx;
  const int row0 = by << 7, col0 = bx << 7;
  const int tid = threadIdx.x;
  const int wave = tid >> 6, lane = tid & 63;
  const int wr = (wave >> 1) * 64, wc = (wave & 1) * 64;
  const int lr = lane & 15, lg = lane >> 4;

  f32x4 acc[4][4];
#pragma unroll
  for (int m = 0; m < 4; ++m)
#pragma unroll
    for (int n = 0; n < 4; ++n) acc[m][n] = (f32x4)0.0f;

  const int srow = wave * 32 + (lane >> 3);
  const int scol = ((lane & 7) ^ (lane >> 3)) * 8;
  const u16* gA = A + (size_t)(row0 + srow) * K + scol;
  const u16* gB = Bt + (size_t)(col0 + srow) * K + scol;
  const size_t rstep = (size_t)8 * K;
  u16* lA = &As[(wave * 32) * BK];
  u16* lB = &Bs[(wave * 32) * BK];

  const int rsw = (lr & 7) * 8;  // read-side swizzle

  for (int k0 = 0; k0 < K; k0 += BK) {
#pragma unroll
    for (int c = 0; c < 4; ++c) {
      gload_lds16(gA + c * rstep + k0, lA + c * 8 * BK);
      gload_lds16(gB + c * rstep + k0, lB + c * 8 * BK);
    }
    __syncthreads();
#pragma unroll
    for (int sub = 0; sub < 2; ++sub) {
      const int co = (sub * 32 + lg * 8) ^ rsw;
      bf16x8 af[4], bfr[4];
#pragma unroll
      for (int m = 0; m < 4; ++m)
        af[m] = *reinterpret_cast<const bf16x8*>(&As[(wr + m * 16 + lr) * BK + co]);
#pragma unroll
      for (int n = 0; n < 4; ++n)
        bfr[n] = *reinterpret_cast<const bf16x8*>(&Bs[(wc + n * 16 + lr) * BK + co]);
#pragma unroll
      for (int m = 0; m < 4; ++m)
#pragma unroll
        for (int n = 0; n < 4; ++n)
          acc[m][n] = __builtin_amdgcn_mfma_f32_16x16x32_bf16(af[m], bfr[n], acc[m][n], 0, 0, 0);
    }
    __syncthreads();
  }

#pragma unroll
  for (int m = 0; m < 4; ++m) {
    const int r = row0 + wr + m * 16 + lg * 4;
#pragma unroll
    for (int n = 0; n < 4; ++n) {
      const int c = col0 + wc + n * 16 + lr;
#pragma unroll
      for (int i = 0; i < 4; ++i) {
        float v = acc[m][n][i];
        if (OUT_MODE == 0)
          ((u16*)Cp)[(size_t)(r + i) * N + c] = f2bf(v);
        else if (OUT_MODE == 1)
          ((float*)Cp)[(size_t)(r + i) * N + c] = v + bias[c];
        else {  // 3: q | latent split
          if (c < 2048)
            ((u16*)Cp)[(size_t)(r + i) * 2048 + c] = f2bf(v * scale);
          else
            ((u16*)Cp2)[(size_t)(r + i) * 256 + (c - 2048)] = f2bf(v);
        }
      }
    }
  }
}

// ---------- causal flash attention: 8-wave blocks, 256 q-rows, KVBLK=128 ----------
// EQUAL-JOB decomposition: each bh's 72 tiles split into 8 jobs of EXACTLY 9
// tiles via job chaining (a block runs up to 2 segments from different strips):
//   J0 s7[0,9)p0 | J1 s7[9,16)p1 + s0 | J2 s6[0,9)p0 | J3 s6[9,14)p1 + s1
//   J4 s5[0,9)p0 | J5 s5[9,12)p1 + s2 | J6 s4[0,9)p0 | J7 s4[9,10)p1 + s3
// 256 blocks = 1/CU -> makespan 9 tiles. Strips 4..7 split (2 parts, merged by
// k_comb). Block order job*32+bh keeps a bh's jobs on one XCD.
// Fixed-max softmax: P = exp2(s); only l tracked, summed post-PV.
__device__ __constant__ const signed char S_qb[16] = {7,0, 7,0, 6,0, 6,1, 5,0, 5,2, 4,0, 4,3};
__device__ __constant__ const signed char S_k0[16] = {0,0, 9,0, 0,0, 9,0, 0,0, 9,0, 0,0, 9,0};
__device__ __constant__ const signed char S_k1[16] = {9,0, 16,2, 9,0, 14,4, 9,0, 12,6, 9,0, 10,8};
__device__ __constant__ const signed char S_pm[16] = {0,0, 1,-1, 0,0, 1,-1, 0,0, 1,-1, 0,0, 1,-1};

__global__ __launch_bounds__(512) void k_attn(const u16* __restrict__ Q,
                                              const u16* __restrict__ KV,
                                              u16* __restrict__ O,
                                              u16* __restrict__ o_part,
                                              float* __restrict__ lbuf) {
  __shared__ __align__(16) u16 Ks[128 * 128];
  __shared__ __align__(16) u16 Vt[128 * 128];
  const int job = blockIdx.x >> 5, bh = blockIdx.x & 31;
  const int b = bh >> 4, h = bh & 15;
  const u16* Qb = Q + (size_t)b * Ss * D_OUT + h * HD;
  const u16* Kb = KV + (size_t)b * Ss * (2 * D_OUT) + h * HD;
  const u16* Vb = Kb + D_OUT;
  u16* Ob = O + (size_t)b * Ss * D_OUT + h * HD;

  const int tid = threadIdx.x, wave = tid >> 6, lane = tid & 63;
  const int lo = lane & 31, hi = lane >> 5;

  const int sr = tid >> 2, sc = tid & 3;
  const int vk = (tid & 31) * 4, vd = (tid >> 5) * 8;
  const size_t kvstep = (size_t)128 * 2 * D_OUT;
  const int ksw = (sr & 7) ^ (((sr >> 3) & 3) << 1);
  const int krd = ((lo & 7) * 8) ^ (((lo >> 3) & 3) << 4);

  for (int seg = 0; seg < 2; ++seg) {
    const int kt1 = S_k1[job * 2 + seg];
    if (kt1 == 0) break;  // no second segment
    const int qb = S_qb[job * 2 + seg];
    const int kt0 = S_k0[job * 2 + seg];
    const int pm = S_pm[job * 2 + seg];  // -1 whole, else part index
    const int q0w = qb * 256 + wave * 32;

    // Q fragments for this segment
    bf16x8 qf[8];
    {
      const u16* qsrc = Qb + (size_t)(q0w + lo) * D_OUT + hi * 8;
#pragma unroll
      for (int ds = 0; ds < 8; ++ds)
        qf[ds] = *reinterpret_cast<const bf16x8*>(qsrc + ds * 16);
    }

    f32x16 ctx[4];
#pragma unroll
    for (int dt = 0; dt < 4; ++dt) ctx[dt] = (f32x16)0.0f;
    float lrow = 0.0f;

    const u16* kg = Kb + (size_t)kt0 * kvstep + (size_t)sr * (2 * D_OUT) + sc * 8;
    const u16* vg = Vb + (size_t)kt0 * kvstep + (size_t)vk * (2 * D_OUT) + vd;

    int4 kreg[4];
    u16x8 vreg[4];
#pragma unroll
    for (int c = 0; c < 4; ++c) {
      kreg[c] = *reinterpret_cast<const int4*>(kg + c * 32);
      vreg[c] = *reinterpret_cast<const u16x8*>(vg + (size_t)c * (2 * D_OUT));
    }

    for (int kt = kt0; kt < kt1; ++kt) {
#pragma unroll
      for (int c = 0; c < 4; ++c)
        *reinterpret_cast<int4*>(&Ks[sr * 128 + (((sc + 4 * c) ^ ksw) * 8)]) = kreg[c];
#pragma unroll
      for (int jj = 0; jj < 8; ++jj) {
        const int vcol = (vk ^ (jj * 8)) ^ ((((vd + jj) >> 3) & 3) << 4);
        u16x4 pk = {vreg[0][jj], vreg[1][jj], vreg[2][jj], vreg[3][jj]};
        *reinterpret_cast<u16x4*>(&Vt[(vd + jj) * 128 + vcol]) = pk;
      }
      if (kt + 1 < kt1) {
        const u16* kn = kg + (size_t)(kt + 1 - kt0) * kvstep;
        const u16* vn = vg + (size_t)(kt + 1 - kt0) * kvstep;
#pragma unroll
        for (int c = 0; c < 4; ++c) {
          kreg[c] = *reinterpret_cast<const int4*>(kn + c * 32);
          vreg[c] = *reinterpret_cast<const u16x8*>(vn + (size_t)c * (2 * D_OUT));
        }
      }
      __syncthreads();

#pragma unroll
      for (int sub = 0; sub < 2; ++sub) {
        const int kbs = kt * 128 + sub * 64;
        if (kbs <= q0w + 31) {
          f32x16 s0 = (f32x16)0.0f, s1 = (f32x16)0.0f;
          __builtin_amdgcn_s_setprio(1);
#pragma unroll
          for (int ds = 0; ds < 8; ++ds) {
            const int off = (16 * ds + 8 * hi) ^ krd;
            bf16x8 a0 = *reinterpret_cast<const bf16x8*>(&Ks[(sub * 64 + lo) * 128 + off]);
            bf16x8 a1 = *reinterpret_cast<const bf16x8*>(&Ks[(sub * 64 + 32 + lo) * 128 + off]);
            s0 = __builtin_amdgcn_mfma_f32_32x32x16_bf16(a0, qf[ds], s0, 0, 0, 0);
            s1 = __builtin_amdgcn_mfma_f32_32x32x16_bf16(a1, qf[ds], s1, 0, 0, 0);
          }
          __builtin_amdgcn_s_setprio(0);

          if (kbs + 63 > q0w) {
            const int qg = q0w + lo;
#pragma unroll
            for (int r = 0; r < 16; ++r) {
              const int koff = kbs + (r & 3) + 8 * (r >> 2) + 4 * hi;
              if (koff > qg) s0[r] = NEG_BIG;
              if (koff + 32 > qg) s1[r] = NEG_BIG;
            }
          }

#pragma unroll
          for (int r = 0; r < 16; ++r) s0[r] = fexp2(s0[r]);
#pragma unroll
          for (int r = 0; r < 16; ++r) s1[r] = fexp2(s1[r]);

          bf16x8 pa[4];
#pragma unroll
          for (int g = 0; g < 2; ++g) {
            const f32x16& sg = g ? s1 : s0;
#pragma unroll
            for (int half = 0; half < 2; ++half) {
              const int rb = half * 8;
              unsigned w0 = cvtpk(sg[rb + 0], sg[rb + 1]);
              unsigned w2 = cvtpk(sg[rb + 4], sg[rb + 5]);
              unsigned w1 = cvtpk(sg[rb + 2], sg[rb + 3]);
              unsigned w3 = cvtpk(sg[rb + 6], sg[rb + 7]);
              swap32(w0, w2);
              swap32(w1, w3);
              u32x4 fr = {w0, w1, w2, w3};
              pa[2 * g + half] = __builtin_bit_cast(bf16x8, fr);
            }
          }

          __builtin_amdgcn_s_setprio(1);
#pragma unroll
          for (int dt = 0; dt < 4; ++dt) {
            const int vrow = 32 * dt + lo;
#pragma unroll
            for (int ks = 0; ks < 4; ++ks) {
              const int off = sub * 64 + ((16 * ks + 8 * hi) ^ krd);
              bf16x8 bv = *reinterpret_cast<const bf16x8*>(&Vt[vrow * 128 + off]);
              ctx[dt] = __builtin_amdgcn_mfma_f32_32x32x16_bf16(pa[ks], bv, ctx[dt], 0, 0, 0);
            }
          }
          __builtin_amdgcn_s_setprio(0);

          float sm[16];
#pragma unroll
          for (int r = 0; r < 16; ++r) sm[r] = s0[r] + s1[r];
#pragma unroll
          for (int w = 8; w >= 1; w >>= 1)
#pragma unroll
            for (int r = 0; r < w; ++r) sm[r] += sm[r + w];
          lrow += sm[0] + __shfl_xor(sm[0], 32);
        }
      }
      __syncthreads();
    }

    if (pm < 0) {
      // whole strip: normalize + store bf16 ctx
      float linv = 1.0f / lrow;
#pragma unroll
      for (int r = 0; r < 16; ++r) {
        float lb = __shfl(linv, ((r & 3) + 8 * (r >> 2)) + 4 * hi);
        const int qr = q0w + (r & 3) + 8 * (r >> 2) + 4 * hi;
#pragma unroll
        for (int dt = 0; dt < 4; ++dt)
          Ob[(size_t)qr * D_OUT + dt * 32 + lo] = f2bf(ctx[dt][r] * lb);
      }
    } else {
      // split strip part: store unnormalized partial + per-row l
      const int pi = bh * 8 + (qb - 4) * 2 + pm;
      u16* po = o_part + (size_t)pi * (256 * 128);
      float* pl = lbuf + (size_t)pi * 256;
#pragma unroll
      for (int r = 0; r < 16; ++r) {
        const int rl = wave * 32 + (r & 3) + 8 * (r >> 2) + 4 * hi;
#pragma unroll
        for (int dt = 0; dt < 4; ++dt)
          po[rl * 128 + dt * 32 + lo] = f2bf(ctx[dt][r]);
      }
      if (hi == 0) pl[wave * 32 + lo] = lrow;
    }
    __syncthreads();  // LDS safe before next segment's staging
  }
}

// ---------- combine split-strip partials (strips 4..7, always 2 parts) ----------
__global__ __launch_bounds__(256) void k_comb(const u16* __restrict__ o_part,
                                              const float* __restrict__ lbuf,
                                              u16* __restrict__ O) {
  const int sb = blockIdx.x >> 2;   // strip 0..127
  const int rg = blockIdx.x & 3;    // row group (64 rows)
  const int bh = sb >> 2, js = sb & 3, qb = 4 + js;
  const int b = bh >> 4, h = bh & 15;
  u16* Ob = O + (size_t)b * Ss * D_OUT + h * HD;
  const int base = bh * 8 + js * 2;
  const u16* po0 = o_part + (size_t)base * (256 * 128);
  const u16* po1 = po0 + 256 * 128;
  const float* pl0 = lbuf + (size_t)base * 256;
  const float* pl1 = pl0 + 256;
  const int tid = threadIdx.x;
  const int r0 = tid >> 4, dg = (tid & 15) * 8;
#pragma unroll
  for (int rp = 0; rp < 4; ++rp) {
    const int row = rg * 64 + rp * 16 + r0;
    const float inv = 1.0f / (pl0[row] + pl1[row]);
    u16x8 o1 = *reinterpret_cast<const u16x8*>(po0 + row * 128 + dg);
    u16x8 o2 = *reinterpret_cast<const u16x8*>(po1 + row * 128 + dg);
    u16x8 o;
#pragma unroll
    for (int j = 0; j < 8; ++j)
      o[j] = f2bf((bf2f(o1[j]) + bf2f(o2[j])) * inv);
    *reinterpret_cast<u16x8*>(&Ob[(size_t)(qb * 256 + row) * D_OUT + dg]) = o;
  }
}

extern "C" void kernel_launch(void* const* d_in, const int* in_sizes, int n_in,
                              void* d_out, int out_size, void* d_ws, size_t ws_size,
                              hipStream_t stream) {
  const float* x    = (const float*)d_in[0];
  const float* Wq   = (const float*)d_in[1];
  const float* Wdkv = (const float*)d_in[2];
  const float* Wukv = (const float*)d_in[3];
  const float* Wout = (const float*)d_in[4];
  const float* bout = (const float*)d_in[5];
  float* out = (float*)d_out;

  char* ws = (char*)d_ws;
  size_t off = 0;
  auto alloc = [&](size_t bytes) -> void* {
    void* p = ws + off;
    off += (bytes + 255) & ~(size_t)255;
    return p;
  };
  u16* xb    = (u16*)alloc((size_t)Mtot * D_IN * 2);
  u16* wcat  = (u16*)alloc((size_t)(D_OUT + LAT) * D_IN * 2);  // [Wq^T ; Wdkv^T]
  u16* wukvT = (u16*)alloc((size_t)2 * D_OUT * LAT * 2);
  u16* woutT = (u16*)alloc((size_t)D_IN * D_OUT * 2);
  u16* q     = (u16*)alloc((size_t)Mtot * D_OUT * 2);
  u16* lat   = (u16*)alloc((size_t)Mtot * LAT * 2);
  u16* kv    = (u16*)alloc((size_t)Mtot * 2 * D_OUT * 2);
  u16* ctx   = (u16*)alloc((size_t)Mtot * D_OUT * 2);
  u16* opart = (u16*)alloc((size_t)256 * 256 * 128 * 2);  // 16.8 MB (32 bh x 8 parts)
  float* lbp = (float*)alloc((size_t)256 * 256 * 4);      // 0.26 MB

  // x convert + all weight transposes in ONE dispatch
  k_cvt_all<<<dim3(8192 + 9728), dim3(32, 8), 0, stream>>>(
      x, xb, Wq, wcat, Wdkv, wcat + (size_t)D_OUT * D_IN, Wukv, wukvT, Wout, woutT);

  // [q | latent] = x @ [Wq | Wdkv]; q scaled by QSCALE in epilogue
  k_gemm<3><<<(Mtot / 128) * ((D_OUT + LAT) / 128), 256, 0, stream>>>(
      xb, wcat, q, lat, nullptr, QSCALE, Mtot, D_OUT + LAT, D_IN);
  // kv = latent @ Wukv
  k_gemm<0><<<(Mtot / 128) * (2 * D_OUT / 128), 256, 0, stream>>>(
      lat, wukvT, kv, nullptr, nullptr, 1.0f, Mtot, 2 * D_OUT, LAT);
  // attention (8 equal 9-tile jobs x 32 bh = 256 blocks) + combine
  k_attn<<<dim3(8 * 32), 512, 0, stream>>>(q, kv, ctx, opart, lbp);
  k_comb<<<dim3(512), 256, 0, stream>>>(opart, lbp, ctx);
  // out = ctx @ Wout + b_out
  k_gemm<1><<<(Mtot / 128) * (D_IN / 128), 256, 0, stream>>>(
      ctx, woutT, out, nullptr, bout, 1.0f, Mtot, D_IN, D_OUT);
}

// Round 21
// 192.779 us; speedup vs baseline: 1.1152x; 1.0246x over previous
//
#include <hip/hip_runtime.h>
#include <hip/hip_bf16.h>

typedef short bf16x8 __attribute__((ext_vector_type(8)));
typedef float f32x4 __attribute__((ext_vector_type(4)));
typedef float f32x16 __attribute__((ext_vector_type(16)));
typedef unsigned int u32x4 __attribute__((ext_vector_type(4)));
typedef unsigned short u16;
typedef unsigned short u16x4 __attribute__((ext_vector_type(4)));
typedef unsigned short u16x8 __attribute__((ext_vector_type(8)));

constexpr int D_IN = 2048, D_OUT = 2048, NH = 16, HD = 128, LAT = 256;
constexpr int Bb = 2, Ss = 2048, Mtot = Bb * Ss;  // 4096

constexpr float QSCALE = 0.08838834764831845f * 1.4426950408889634f;
constexpr float NEG_BIG = -3.0e38f;

__device__ __forceinline__ u16 f2bf(float f) {
  unsigned u = __float_as_uint(f);
  unsigned r = ((u >> 16) & 1u) + 0x7fffu;  // RNE
  return (u16)((u + r) >> 16);
}

__device__ __forceinline__ float bf2f(u16 v) {
  return __uint_as_float((unsigned)v << 16);
}

__device__ __forceinline__ float fexp2(float x) {
#if __has_builtin(__builtin_amdgcn_exp2f)
  return __builtin_amdgcn_exp2f(x);
#else
  return exp2f(x);
#endif
}

__device__ __forceinline__ unsigned cvtpk(float lo, float hi) {
  unsigned r;
  asm("v_cvt_pk_bf16_f32 %0, %1, %2" : "=v"(r) : "v"(lo), "v"(hi));
  return r;
}

__device__ __forceinline__ void swap32(unsigned& a, unsigned& b) {
  asm volatile("v_permlane32_swap_b32 %0, %1" : "+v"(a), "+v"(b));
}

__device__ __forceinline__ void gload_lds16(const u16* g, u16* l) {
  __builtin_amdgcn_global_load_lds((const __attribute__((address_space(1))) void*)g,
                                   (__attribute__((address_space(3))) void*)l, 16, 0, 0);
}

// ---------- merged convert: x f32->bf16 (blocks 0..8191) + 4 weight
// transposes [K][N] f32 -> [N][K] bf16 (blocks 8192..17919), one dispatch ----
__global__ void k_cvt_all(const float* __restrict__ x, u16* __restrict__ xb,
                          const float* __restrict__ w0, u16* __restrict__ o0,
                          const float* __restrict__ w1, u16* __restrict__ o1,
                          const float* __restrict__ w2, u16* __restrict__ o2,
                          const float* __restrict__ w3, u16* __restrict__ o3) {
  int id = blockIdx.x;
  const int tx = threadIdx.x, ty = threadIdx.y;
  if (id < 8192) {  // flat convert: 1024 elems per block
    const int i = id * 1024 + (ty * 32 + tx) * 4;
    float4 v = *reinterpret_cast<const float4*>(x + i);
    ushort4 o;
    o.x = f2bf(v.x); o.y = f2bf(v.y); o.z = f2bf(v.z); o.w = f2bf(v.w);
    *reinterpret_cast<ushort4*>(xb + i) = o;
    return;
  }
  id -= 8192;
  __shared__ float t[32][33];
  const float* in;
  u16* out;
  int K, N, bx, by;
  if (id < 4096)      { in = w0; out = o0; K = 2048; N = 2048; bx = (id & 63) * 32; by = (id >> 6) * 32; }
  else if (id < 4608) { id -= 4096; in = w1; out = o1; K = 2048; N = 256;  bx = (id & 7) * 32;  by = (id >> 3) * 32; }
  else if (id < 5632) { id -= 4608; in = w2; out = o2; K = 256;  N = 4096; bx = (id & 127) * 32; by = (id >> 7) * 32; }
  else                { id -= 5632; in = w3; out = o3; K = 2048; N = 2048; bx = (id & 63) * 32; by = (id >> 6) * 32; }
#pragma unroll
  for (int j = 0; j < 32; j += 8)
    t[ty + j][tx] = in[(size_t)(by + ty + j) * N + bx + tx];
  __syncthreads();
#pragma unroll
  for (int j = 0; j < 32; j += 8)
    out[(size_t)(bx + ty + j) * K + by + tx] = f2bf(t[tx][ty + j]);
}

// ---------- GEMM: C[M,N] = A[M,K](bf16 rm) x Bt[N,K](bf16 rm)^T ----------
// 128x128 tile, BK=64, 4 waves, 32x32x16 MFMA (2382 vs 2075 TF for 16x16 ->
// ~13% faster matrix pipe, half the MFMA issue). Two-level both-sides XOR
// swizzle: write via pre-swizzled global source (linear gload_lds dest),
// read offset (ks*16+8hi) ^ (lo&7)*8 ^ (lo>>3)<<4 (attn-verified layout).
// OUT_MODE 0: bf16; 1: f32 + bias; 3: split (c<2048 -> Cp*scale, else Cp2).
template <int OUT_MODE>
__global__ __launch_bounds__(256) void k_gemm(const u16* __restrict__ A,
                                              const u16* __restrict__ Bt,
                                              void* __restrict__ Cp,
                                              void* __restrict__ Cp2,
                                              const float* __restrict__ bias,
                                              float scale, int M, int N, int K) {
  constexpr int BK = 64;
  __shared__ __align__(16) u16 As[128 * BK];  // 16 KB
  __shared__ __align__(16) u16 Bs[128 * BK];  // 16 KB
  const int nwg = gridDim.x;
  int bid = blockIdx.x;
  bid = (bid & 7) * (nwg >> 3) + (bid >> 3);  // bijective XCD swizzle (nwg%8==0)
  const int nbx = N >> 7;
  const int bx = bid % nbx, by = bid / nbx;
  const int row0 = by << 7, col0 = bx << 7;
  const int tid = threadIdx.x;
  const int wave = tid >> 6, lane = tid & 63;
  const int wr = (wave >> 1) * 64, wc = (wave & 1) * 64;
  const int lo = lane & 31, hi = lane >> 5;

  f32x16 acc[2][2];
#pragma unroll
  for (int m = 0; m < 2; ++m)
#pragma unroll
    for (int n = 0; n < 2; ++n) acc[m][n] = (f32x16)0.0f;

  // staging source pointers: call c covers rows wave*32 + c*8 + (lane>>3);
  // source col = ((lane&7)^(lane>>3))*8 ^ (c<<4)  [2-level pre-swizzle]
  const u16* gA[4];
  const u16* gB[4];
#pragma unroll
  for (int c = 0; c < 4; ++c) {
    const int srow = wave * 32 + c * 8 + (lane >> 3);
    const int scol = (((lane & 7) ^ (lane >> 3)) * 8) ^ (c << 4);
    gA[c] = A + (size_t)(row0 + srow) * K + scol;
    gB[c] = Bt + (size_t)(col0 + srow) * K + scol;
  }
  u16* lA = &As[(wave * 32) * BK];
  u16* lB = &Bs[(wave * 32) * BK];

  const int krd = ((lo & 7) * 8) ^ ((lo >> 3) << 4);  // read-side swizzle

  for (int k0 = 0; k0 < K; k0 += BK) {
#pragma unroll
    for (int c = 0; c < 4; ++c) {
      gload_lds16(gA[c] + k0, lA + c * 8 * BK);
      gload_lds16(gB[c] + k0, lB + c * 8 * BK);
    }
    __syncthreads();
#pragma unroll
    for (int ks = 0; ks < 4; ++ks) {
      const int co = (ks * 16 + hi * 8) ^ krd;
      bf16x8 af[2], bfb[2];
#pragma unroll
      for (int mb = 0; mb < 2; ++mb)
        af[mb] = *reinterpret_cast<const bf16x8*>(&As[(wr + mb * 32 + lo) * BK + co]);
#pragma unroll
      for (int nb = 0; nb < 2; ++nb)
        bfb[nb] = *reinterpret_cast<const bf16x8*>(&Bs[(wc + nb * 32 + lo) * BK + co]);
#pragma unroll
      for (int mb = 0; mb < 2; ++mb)
#pragma unroll
        for (int nb = 0; nb < 2; ++nb)
          acc[mb][nb] = __builtin_amdgcn_mfma_f32_32x32x16_bf16(af[mb], bfb[nb], acc[mb][nb], 0, 0, 0);
    }
    __syncthreads();
  }

  // epilogue: C/D layout col=lane&31, row=(i&3)+8*(i>>2)+4*hi (attn-verified)
#pragma unroll
  for (int mb = 0; mb < 2; ++mb) {
#pragma unroll
    for (int nb = 0; nb < 2; ++nb) {
      const int c = col0 + wc + nb * 32 + lo;
#pragma unroll
      for (int i = 0; i < 16; ++i) {
        const int r = row0 + wr + mb * 32 + (i & 3) + 8 * (i >> 2) + 4 * hi;
        float v = acc[mb][nb][i];
        if (OUT_MODE == 0)
          ((u16*)Cp)[(size_t)r * N + c] = f2bf(v);
        else if (OUT_MODE == 1)
          ((float*)Cp)[(size_t)r * N + c] = v + bias[c];
        else {  // 3: q | latent split
          if (c < 2048)
            ((u16*)Cp)[(size_t)r * 2048 + c] = f2bf(v * scale);
          else
            ((u16*)Cp2)[(size_t)r * 256 + (c - 2048)] = f2bf(v);
        }
      }
    }
  }
}

// ---------- causal flash attention: 8-wave blocks, 256 q-rows, KVBLK=128 ----------
// EQUAL-JOB decomposition: 8 jobs of exactly 9 tiles per bh (job chaining),
// 256 blocks = 1/CU -> makespan 9 tiles. Strips 4..7 split (2 parts, merged
// by k_comb). Fixed-max softmax: P = exp2(s); only l tracked, summed post-PV.
__device__ __constant__ const signed char S_qb[16] = {7,0, 7,0, 6,0, 6,1, 5,0, 5,2, 4,0, 4,3};
__device__ __constant__ const signed char S_k0[16] = {0,0, 9,0, 0,0, 9,0, 0,0, 9,0, 0,0, 9,0};
__device__ __constant__ const signed char S_k1[16] = {9,0, 16,2, 9,0, 14,4, 9,0, 12,6, 9,0, 10,8};
__device__ __constant__ const signed char S_pm[16] = {0,0, 1,-1, 0,0, 1,-1, 0,0, 1,-1, 0,0, 1,-1};

__global__ __launch_bounds__(512) void k_attn(const u16* __restrict__ Q,
                                              const u16* __restrict__ KV,
                                              u16* __restrict__ O,
                                              u16* __restrict__ o_part,
                                              float* __restrict__ lbuf) {
  __shared__ __align__(16) u16 Ks[128 * 128];
  __shared__ __align__(16) u16 Vt[128 * 128];
  const int job = blockIdx.x >> 5, bh = blockIdx.x & 31;
  const int b = bh >> 4, h = bh & 15;
  const u16* Qb = Q + (size_t)b * Ss * D_OUT + h * HD;
  const u16* Kb = KV + (size_t)b * Ss * (2 * D_OUT) + h * HD;
  const u16* Vb = Kb + D_OUT;
  u16* Ob = O + (size_t)b * Ss * D_OUT + h * HD;

  const int tid = threadIdx.x, wave = tid >> 6, lane = tid & 63;
  const int lo = lane & 31, hi = lane >> 5;

  const int sr = tid >> 2, sc = tid & 3;
  const int vk = (tid & 31) * 4, vd = (tid >> 5) * 8;
  const size_t kvstep = (size_t)128 * 2 * D_OUT;
  const int ksw = (sr & 7) ^ (((sr >> 3) & 3) << 1);
  const int krd = ((lo & 7) * 8) ^ (((lo >> 3) & 3) << 4);

  for (int seg = 0; seg < 2; ++seg) {
    const int kt1 = S_k1[job * 2 + seg];
    if (kt1 == 0) break;  // no second segment
    const int qb = S_qb[job * 2 + seg];
    const int kt0 = S_k0[job * 2 + seg];
    const int pm = S_pm[job * 2 + seg];  // -1 whole, else part index
    const int q0w = qb * 256 + wave * 32;

    // Q fragments for this segment
    bf16x8 qf[8];
    {
      const u16* qsrc = Qb + (size_t)(q0w + lo) * D_OUT + hi * 8;
#pragma unroll
      for (int ds = 0; ds < 8; ++ds)
        qf[ds] = *reinterpret_cast<const bf16x8*>(qsrc + ds * 16);
    }

    f32x16 ctx[4];
#pragma unroll
    for (int dt = 0; dt < 4; ++dt) ctx[dt] = (f32x16)0.0f;
    float lrow = 0.0f;

    const u16* kg = Kb + (size_t)kt0 * kvstep + (size_t)sr * (2 * D_OUT) + sc * 8;
    const u16* vg = Vb + (size_t)kt0 * kvstep + (size_t)vk * (2 * D_OUT) + vd;

    int4 kreg[4];
    u16x8 vreg[4];
#pragma unroll
    for (int c = 0; c < 4; ++c) {
      kreg[c] = *reinterpret_cast<const int4*>(kg + c * 32);
      vreg[c] = *reinterpret_cast<const u16x8*>(vg + (size_t)c * (2 * D_OUT));
    }

    for (int kt = kt0; kt < kt1; ++kt) {
#pragma unroll
      for (int c = 0; c < 4; ++c)
        *reinterpret_cast<int4*>(&Ks[sr * 128 + (((sc + 4 * c) ^ ksw) * 8)]) = kreg[c];
#pragma unroll
      for (int jj = 0; jj < 8; ++jj) {
        const int vcol = (vk ^ (jj * 8)) ^ ((((vd + jj) >> 3) & 3) << 4);
        u16x4 pk = {vreg[0][jj], vreg[1][jj], vreg[2][jj], vreg[3][jj]};
        *reinterpret_cast<u16x4*>(&Vt[(vd + jj) * 128 + vcol]) = pk;
      }
      if (kt + 1 < kt1) {
        const u16* kn = kg + (size_t)(kt + 1 - kt0) * kvstep;
        const u16* vn = vg + (size_t)(kt + 1 - kt0) * kvstep;
#pragma unroll
        for (int c = 0; c < 4; ++c) {
          kreg[c] = *reinterpret_cast<const int4*>(kn + c * 32);
          vreg[c] = *reinterpret_cast<const u16x8*>(vn + (size_t)c * (2 * D_OUT));
        }
      }
      __syncthreads();

#pragma unroll
      for (int sub = 0; sub < 2; ++sub) {
        const int kbs = kt * 128 + sub * 64;
        if (kbs <= q0w + 31) {
          f32x16 s0 = (f32x16)0.0f, s1 = (f32x16)0.0f;
          __builtin_amdgcn_s_setprio(1);
#pragma unroll
          for (int ds = 0; ds < 8; ++ds) {
            const int off = (16 * ds + 8 * hi) ^ krd;
            bf16x8 a0 = *reinterpret_cast<const bf16x8*>(&Ks[(sub * 64 + lo) * 128 + off]);
            bf16x8 a1 = *reinterpret_cast<const bf16x8*>(&Ks[(sub * 64 + 32 + lo) * 128 + off]);
            s0 = __builtin_amdgcn_mfma_f32_32x32x16_bf16(a0, qf[ds], s0, 0, 0, 0);
            s1 = __builtin_amdgcn_mfma_f32_32x32x16_bf16(a1, qf[ds], s1, 0, 0, 0);
          }
          __builtin_amdgcn_s_setprio(0);

          if (kbs + 63 > q0w) {
            const int qg = q0w + lo;
#pragma unroll
            for (int r = 0; r < 16; ++r) {
              const int koff = kbs + (r & 3) + 8 * (r >> 2) + 4 * hi;
              if (koff > qg) s0[r] = NEG_BIG;
              if (koff + 32 > qg) s1[r] = NEG_BIG;
            }
          }

#pragma unroll
          for (int r = 0; r < 16; ++r) s0[r] = fexp2(s0[r]);
#pragma unroll
          for (int r = 0; r < 16; ++r) s1[r] = fexp2(s1[r]);

          bf16x8 pa[4];
#pragma unroll
          for (int g = 0; g < 2; ++g) {
            const f32x16& sg = g ? s1 : s0;
#pragma unroll
            for (int half = 0; half < 2; ++half) {
              const int rb = half * 8;
              unsigned w0 = cvtpk(sg[rb + 0], sg[rb + 1]);
              unsigned w2 = cvtpk(sg[rb + 4], sg[rb + 5]);
              unsigned w1 = cvtpk(sg[rb + 2], sg[rb + 3]);
              unsigned w3 = cvtpk(sg[rb + 6], sg[rb + 7]);
              swap32(w0, w2);
              swap32(w1, w3);
              u32x4 fr = {w0, w1, w2, w3};
              pa[2 * g + half] = __builtin_bit_cast(bf16x8, fr);
            }
          }

          __builtin_amdgcn_s_setprio(1);
#pragma unroll
          for (int dt = 0; dt < 4; ++dt) {
            const int vrow = 32 * dt + lo;
#pragma unroll
            for (int ks = 0; ks < 4; ++ks) {
              const int off = sub * 64 + ((16 * ks + 8 * hi) ^ krd);
              bf16x8 bv = *reinterpret_cast<const bf16x8*>(&Vt[vrow * 128 + off]);
              ctx[dt] = __builtin_amdgcn_mfma_f32_32x32x16_bf16(pa[ks], bv, ctx[dt], 0, 0, 0);
            }
          }
          __builtin_amdgcn_s_setprio(0);

          float sm[16];
#pragma unroll
          for (int r = 0; r < 16; ++r) sm[r] = s0[r] + s1[r];
#pragma unroll
          for (int w = 8; w >= 1; w >>= 1)
#pragma unroll
            for (int r = 0; r < w; ++r) sm[r] += sm[r + w];
          lrow += sm[0] + __shfl_xor(sm[0], 32);
        }
      }
      __syncthreads();
    }

    if (pm < 0) {
      // whole strip: normalize + store bf16 ctx
      float linv = 1.0f / lrow;
#pragma unroll
      for (int r = 0; r < 16; ++r) {
        float lb = __shfl(linv, ((r & 3) + 8 * (r >> 2)) + 4 * hi);
        const int qr = q0w + (r & 3) + 8 * (r >> 2) + 4 * hi;
#pragma unroll
        for (int dt = 0; dt < 4; ++dt)
          Ob[(size_t)qr * D_OUT + dt * 32 + lo] = f2bf(ctx[dt][r] * lb);
      }
    } else {
      // split strip part: store unnormalized partial + per-row l
      const int pi = bh * 8 + (qb - 4) * 2 + pm;
      u16* po = o_part + (size_t)pi * (256 * 128);
      float* pl = lbuf + (size_t)pi * 256;
#pragma unroll
      for (int r = 0; r < 16; ++r) {
        const int rl = wave * 32 + (r & 3) + 8 * (r >> 2) + 4 * hi;
#pragma unroll
        for (int dt = 0; dt < 4; ++dt)
          po[rl * 128 + dt * 32 + lo] = f2bf(ctx[dt][r]);
      }
      if (hi == 0) pl[wave * 32 + lo] = lrow;
    }
    __syncthreads();  // LDS safe before next segment's staging
  }
}

// ---------- combine split-strip partials (strips 4..7, always 2 parts) ----------
__global__ __launch_bounds__(256) void k_comb(const u16* __restrict__ o_part,
                                              const float* __restrict__ lbuf,
                                              u16* __restrict__ O) {
  const int sb = blockIdx.x >> 2;   // strip 0..127
  const int rg = blockIdx.x & 3;    // row group (64 rows)
  const int bh = sb >> 2, js = sb & 3, qb = 4 + js;
  const int b = bh >> 4, h = bh & 15;
  u16* Ob = O + (size_t)b * Ss * D_OUT + h * HD;
  const int base = bh * 8 + js * 2;
  const u16* po0 = o_part + (size_t)base * (256 * 128);
  const u16* po1 = po0 + 256 * 128;
  const float* pl0 = lbuf + (size_t)base * 256;
  const float* pl1 = pl0 + 256;
  const int tid = threadIdx.x;
  const int r0 = tid >> 4, dg = (tid & 15) * 8;
#pragma unroll
  for (int rp = 0; rp < 4; ++rp) {
    const int row = rg * 64 + rp * 16 + r0;
    const float inv = 1.0f / (pl0[row] + pl1[row]);
    u16x8 o1 = *reinterpret_cast<const u16x8*>(po0 + row * 128 + dg);
    u16x8 o2 = *reinterpret_cast<const u16x8*>(po1 + row * 128 + dg);
    u16x8 o;
#pragma unroll
    for (int j = 0; j < 8; ++j)
      o[j] = f2bf((bf2f(o1[j]) + bf2f(o2[j])) * inv);
    *reinterpret_cast<u16x8*>(&Ob[(size_t)(qb * 256 + row) * D_OUT + dg]) = o;
  }
}

extern "C" void kernel_launch(void* const* d_in, const int* in_sizes, int n_in,
                              void* d_out, int out_size, void* d_ws, size_t ws_size,
                              hipStream_t stream) {
  const float* x    = (const float*)d_in[0];
  const float* Wq   = (const float*)d_in[1];
  const float* Wdkv = (const float*)d_in[2];
  const float* Wukv = (const float*)d_in[3];
  const float* Wout = (const float*)d_in[4];
  const float* bout = (const float*)d_in[5];
  float* out = (float*)d_out;

  char* ws = (char*)d_ws;
  size_t off = 0;
  auto alloc = [&](size_t bytes) -> void* {
    void* p = ws + off;
    off += (bytes + 255) & ~(size_t)255;
    return p;
  };
  u16* xb    = (u16*)alloc((size_t)Mtot * D_IN * 2);
  u16* wcat  = (u16*)alloc((size_t)(D_OUT + LAT) * D_IN * 2);  // [Wq^T ; Wdkv^T]
  u16* wukvT = (u16*)alloc((size_t)2 * D_OUT * LAT * 2);
  u16* woutT = (u16*)alloc((size_t)D_IN * D_OUT * 2);
  u16* q     = (u16*)alloc((size_t)Mtot * D_OUT * 2);
  u16* lat   = (u16*)alloc((size_t)Mtot * LAT * 2);
  u16* kv    = (u16*)alloc((size_t)Mtot * 2 * D_OUT * 2);
  u16* ctx   = (u16*)alloc((size_t)Mtot * D_OUT * 2);
  u16* opart = (u16*)alloc((size_t)256 * 256 * 128 * 2);  // 16.8 MB (32 bh x 8 parts)
  float* lbp = (float*)alloc((size_t)256 * 256 * 4);      // 0.26 MB

  // x convert + all weight transposes in ONE dispatch
  k_cvt_all<<<dim3(8192 + 9728), dim3(32, 8), 0, stream>>>(
      x, xb, Wq, wcat, Wdkv, wcat + (size_t)D_OUT * D_IN, Wukv, wukvT, Wout, woutT);

  // [q | latent] = x @ [Wq | Wdkv]; q scaled by QSCALE in epilogue
  k_gemm<3><<<(Mtot / 128) * ((D_OUT + LAT) / 128), 256, 0, stream>>>(
      xb, wcat, q, lat, nullptr, QSCALE, Mtot, D_OUT + LAT, D_IN);
  // kv = latent @ Wukv
  k_gemm<0><<<(Mtot / 128) * (2 * D_OUT / 128), 256, 0, stream>>>(
      lat, wukvT, kv, nullptr, nullptr, 1.0f, Mtot, 2 * D_OUT, LAT);
  // attention (8 equal 9-tile jobs x 32 bh = 256 blocks) + combine
  k_attn<<<dim3(8 * 32), 512, 0, stream>>>(q, kv, ctx, opart, lbp);
  k_comb<<<dim3(512), 256, 0, stream>>>(opart, lbp, ctx);
  // out = ctx @ Wout + b_out
  k_gemm<1><<<(Mtot / 128) * (D_IN / 128), 256, 0, stream>>>(
      ctx, woutT, out, nullptr, bout, 1.0f, Mtot, D_IN, D_OUT);
}